// Round 2
// baseline (23691.289 us; speedup 1.0000x reference)
//
#include <hip/hip_runtime.h>
#include <hip/hip_bf16.h>
#include <cstdint>
#include <cstddef>

#define Bdim 256
#define Tdim 256
#define Idim 512
#define Hdim 1024
#define Odim 5
#define BH (Bdim * Hdim)

using short8 = __attribute__((ext_vector_type(8))) short;
using f32x4  = __attribute__((ext_vector_type(4))) float;

__device__ __forceinline__ short bf16_of(float f) {
  unsigned u = __builtin_bit_cast(unsigned, f);
  u += 0x7fffu + ((u >> 16) & 1u);
  return (short)(u >> 16);
}

__device__ __forceinline__ float sigmf(float x) {
  return 1.0f / (1.0f + __expf(-x));
}

// x fp32 [B][T][I] -> bf16 [T][B][I]
__global__ __launch_bounds__(256) void k_cvt_x(const float* __restrict__ src,
                                               short* __restrict__ dst) {
  int e = (blockIdx.x * 256 + threadIdx.x) * 8;
  int row = e >> 9;          // b*T + t
  int i0  = e & 511;
  int b = row >> 8, t = row & 255;
  float4 u = *reinterpret_cast<const float4*>(src + e);
  float4 v = *reinterpret_cast<const float4*>(src + e + 4);
  short8 o = {bf16_of(u.x), bf16_of(u.y), bf16_of(u.z), bf16_of(u.w),
              bf16_of(v.x), bf16_of(v.y), bf16_of(v.z), bf16_of(v.w)};
  *reinterpret_cast<short8*>(dst + (((t << 8) + b) << 9) + i0) = o;
}

__global__ __launch_bounds__(256) void k_init(const float* __restrict__ hidden,
    short* __restrict__ h0b, short* __restrict__ h1b) {
  int i = blockIdx.x * 256 + threadIdx.x;
  if (i < BH) {
    h0b[i] = bf16_of(hidden[i]);
    h1b[i] = bf16_of(hidden[2 * BH + i]);
  }
}

__device__ __forceinline__ void grid_barrier(unsigned* bar, unsigned target) {
  __syncthreads();   // each wave drains its own vmcnt before s_barrier
  if (threadIdx.x == 0) {
    __threadfence(); // release: write-back so other XCDs see h stores
    __hip_atomic_fetch_add(bar, 1u, __ATOMIC_RELEASE, __HIP_MEMORY_SCOPE_AGENT);
    unsigned v;
    do {
      __builtin_amdgcn_s_sleep(1);
      v = __hip_atomic_load(bar, __ATOMIC_ACQUIRE, __HIP_MEMORY_SCOPE_AGENT);
    } while (v < target);
  }
  __syncthreads();
  __threadfence();   // acquire per-wave: invalidate stale L1/L2 lines
}

// Persistent weight-stationary LSTM.
// grid = 256 WGs x 512 threads. WG 0..127: layer0 (8 h-cols each);
// WG 128..255: layer1. Skewed pipeline: round r -> L0 step r, L1 step r-1.
__global__ __launch_bounds__(512, 1) void k_persist(
    const float* __restrict__ W0, const float* __restrict__ b0v,
    const float* __restrict__ W1, const float* __restrict__ b1v,
    const float* __restrict__ hidden,
    const short* __restrict__ xb,     // [T][B][I] bf16
    short* __restrict__ h0A, short* __restrict__ h0B,
    short* __restrict__ h1A, short* __restrict__ h1B,
    float* __restrict__ finals,       // [L][2][B][H] fp32 (in d_out)
    unsigned* __restrict__ bar) {
  extern __shared__ short lw[];       // [32][pitch] bf16 weight slice
  const int tid  = threadIdx.x;
  const int wg   = blockIdx.x;
  const bool isL0 = (wg < 128);
  const int slot  = isL0 ? wg : wg - 128;
  const int hcol0 = slot * 8;
  const int K     = isL0 ? (Hdim + Idim) : (2 * Hdim);
  const int pitch = K + 8;            // pad: row stride 772 dwords -> 2-way max
  const int layer = isL0 ? 0 : 1;
  const float* Wsrc = isL0 ? W0 : W1;
  const float* bsrc = isL0 ? b0v : b1v;

  // ---- stage weight slice into LDS (fp32 -> bf16), rows r = gate*8 + hcol ----
  for (int r = 0; r < 32; ++r) {
    const float* src = Wsrc + (size_t)((r >> 3) * Hdim + hcol0 + (r & 7)) * K;
    short* dst = lw + r * pitch;
    for (int k = tid; k < K; k += 512) dst[k] = bf16_of(src[k]);
  }

  const int lane = tid & 63;
  const int wv   = tid >> 6;          // wave 0..7 -> batch rows [wv*32, wv*32+32)
  const int col  = lane & 15;         // MFMA N-col / A-row index
  const int rg   = lane >> 4;

  // bias: n=0 -> gates f(col<8)/i(col>=8); n=1 -> g/o
  float biasv[2];
  #pragma unroll
  for (int n = 0; n < 2; ++n)
    biasv[n] = bsrc[(n * 2 + (col >= 8 ? 1 : 0)) * Hdim + hcol0 + (col & 7)];

  // c-state in registers (meaningful on lanes col<8); h-final kept for epilogue
  float creg[2][4], hfin[2][4];
  #pragma unroll
  for (int m = 0; m < 2; ++m)
    #pragma unroll
    for (int j = 0; j < 4; ++j) {
      int b = wv * 32 + m * 16 + rg * 4 + j;
      creg[m][j] = hidden[(layer * 2 + 1) * BH + b * Hdim + hcol0 + (col & 7)];
      hfin[m][j] = 0.f;
    }

  short* h0buf[2] = {h0A, h0B};
  short* h1buf[2] = {h1A, h1B};

  __syncthreads();

  const short* lb0 = lw + col * pitch;          // N-tile 0: gates f,i
  const short* lb1 = lw + (16 + col) * pitch;   // N-tile 1: gates g,o
  const int kl = rg * 8;

  for (int r = 0; r <= 256; ++r) {
    const bool active = isL0 ? (r < 256) : (r >= 1);
    if (active) {
      const int t = isL0 ? r : r - 1;
      // A rows: K[0,H) = own h(t-1); K[H,K) = x_t (L0) or h0(t) (L1)
      const short* Ah = isL0 ? h0buf[r & 1] : h1buf[(r + 1) & 1];
      const short* Ax = isL0 ? (xb + (size_t)t * (Bdim * Idim)) : h0buf[r & 1];
      short* hout = isL0 ? h0buf[(r + 1) & 1] : h1buf[r & 1];
      const int xstride = isL0 ? Idim : Hdim;

      f32x4 acc[2][2] = {};
      const short* ah0 = Ah + (wv * 32 + col) * Hdim;
      const short* ah1 = ah0 + 16 * Hdim;
      #pragma unroll 4
      for (int k0 = 0; k0 < Hdim; k0 += 32) {
        int k = k0 + kl;
        short8 a0  = *(const short8*)(ah0 + k);
        short8 a1  = *(const short8*)(ah1 + k);
        short8 bf0 = *(const short8*)(lb0 + k);
        short8 bf1 = *(const short8*)(lb1 + k);
        acc[0][0] = __builtin_amdgcn_mfma_f32_16x16x32_bf16(a0, bf0, acc[0][0], 0, 0, 0);
        acc[1][0] = __builtin_amdgcn_mfma_f32_16x16x32_bf16(a1, bf0, acc[1][0], 0, 0, 0);
        acc[0][1] = __builtin_amdgcn_mfma_f32_16x16x32_bf16(a0, bf1, acc[0][1], 0, 0, 0);
        acc[1][1] = __builtin_amdgcn_mfma_f32_16x16x32_bf16(a1, bf1, acc[1][1], 0, 0, 0);
      }
      const short* ax0 = Ax + (size_t)(wv * 32 + col) * xstride - Hdim;
      const short* ax1 = ax0 + 16 * xstride;
      #pragma unroll 4
      for (int k0 = Hdim; k0 < K; k0 += 32) {
        int k = k0 + kl;
        short8 a0  = *(const short8*)(ax0 + k);
        short8 a1  = *(const short8*)(ax1 + k);
        short8 bf0 = *(const short8*)(lb0 + k);
        short8 bf1 = *(const short8*)(lb1 + k);
        acc[0][0] = __builtin_amdgcn_mfma_f32_16x16x32_bf16(a0, bf0, acc[0][0], 0, 0, 0);
        acc[1][0] = __builtin_amdgcn_mfma_f32_16x16x32_bf16(a1, bf0, acc[1][0], 0, 0, 0);
        acc[0][1] = __builtin_amdgcn_mfma_f32_16x16x32_bf16(a0, bf1, acc[0][1], 0, 0, 0);
        acc[1][1] = __builtin_amdgcn_mfma_f32_16x16x32_bf16(a1, bf1, acc[1][1], 0, 0, 0);
      }
      // fused gates: D row = rg*4+j -> batch; col<8 lanes own h-col hcol0+col
      #pragma unroll
      for (int m = 0; m < 2; ++m) {
        #pragma unroll
        for (int j = 0; j < 4; ++j) {
          float fi  = acc[m][0][j] + biasv[0];
          float go  = acc[m][1][j] + biasv[1];
          float iv_ = __shfl_xor(fi, 8, 64);
          float ov_ = __shfl_xor(go, 8, 64);
          float fv = sigmf(fi), iv = sigmf(iv_);
          float gv = tanhf(go), ov = sigmf(ov_);
          float cn = fv * creg[m][j] + iv * gv;
          creg[m][j] = cn;
          float hn = ov * tanhf(cn);
          hfin[m][j] = hn;
          if (col < 8) {
            int b = wv * 32 + m * 16 + rg * 4 + j;
            hout[b * Hdim + hcol0 + col] = bf16_of(hn);
          }
        }
      }
    }
    if (r < 256) grid_barrier(bar, (unsigned)(r + 1) * 256u);
  }

  // epilogue: finals [L][2][B][H]
  if (col < 8) {
    #pragma unroll
    for (int m = 0; m < 2; ++m)
      #pragma unroll
      for (int j = 0; j < 4; ++j) {
        int b = wv * 32 + m * 16 + rg * 4 + j;
        finals[(layer * 2 + 0) * BH + b * Hdim + hcol0 + col] = hfin[m][j];
        finals[(layer * 2 + 1) * BH + b * Hdim + hcol0 + col] = creg[m][j];
      }
  }
}

__global__ __launch_bounds__(256) void k_outproj(const float* __restrict__ h1f,
    const float* __restrict__ Wout, const float* __restrict__ bout,
    float* __restrict__ out) {
  int b = blockIdx.x;
  int tid = threadIdx.x;
  float hv[4];
  #pragma unroll
  for (int j = 0; j < 4; ++j) hv[j] = h1f[b * Hdim + tid + j * 256];
  __shared__ float red[Odim][4];
  #pragma unroll
  for (int o = 0; o < Odim; ++o) {
    float p = 0.f;
    #pragma unroll
    for (int j = 0; j < 4; ++j) p += hv[j] * Wout[o * Hdim + tid + j * 256];
    #pragma unroll
    for (int s = 32; s > 0; s >>= 1) p += __shfl_down(p, s, 64);
    if ((tid & 63) == 0) red[o][tid >> 6] = p;
  }
  __syncthreads();
  if (tid < Odim)
    out[b * Odim + tid] = red[tid][0] + red[tid][1] + red[tid][2] + red[tid][3] + bout[tid];
}

extern "C" void kernel_launch(void* const* d_in, const int* in_sizes, int n_in,
                              void* d_out, int out_size, void* d_ws, size_t ws_size,
                              hipStream_t stream) {
  const float* x      = (const float*)d_in[0];
  const float* hidden = (const float*)d_in[1];
  const float* W0     = (const float*)d_in[2];
  const float* b0     = (const float*)d_in[3];
  const float* W1     = (const float*)d_in[4];
  const float* b1     = (const float*)d_in[5];
  const float* Wout   = (const float*)d_in[6];
  const float* bout   = (const float*)d_in[7];
  float* out = (float*)d_out;
  float* finals = out + Bdim * Odim;

  char* ws = (char*)d_ws;
  size_t off = 0;
  auto alloc = [&](size_t bytes) {
    void* p = ws + off;
    off += (bytes + 255) & ~(size_t)255;
    return p;
  };
  short* xb16 = (short*)alloc((size_t)Tdim * Bdim * Idim * 2);  // 67.1 MB
  short* h0A  = (short*)alloc((size_t)BH * 2);
  short* h0B  = (short*)alloc((size_t)BH * 2);
  short* h1A  = (short*)alloc((size_t)BH * 2);
  short* h1B  = (short*)alloc((size_t)BH * 2);
  unsigned* bar = (unsigned*)alloc(256);

  k_cvt_x<<<(Tdim * Bdim * Idim) / (256 * 8), 256, 0, stream>>>(x, xb16);
  k_init<<<BH / 256, 256, 0, stream>>>(hidden, h0A, h1A);
  hipMemsetAsync(bar, 0, sizeof(unsigned), stream);

  const int ldsBytes = 32 * (2 * Hdim + 8) * 2;  // 131584 (L1 slice, the max)
  hipFuncSetAttribute((const void*)k_persist,
                      hipFuncAttributeMaxDynamicSharedMemorySize, ldsBytes);
  void* args[] = {(void*)&W0, (void*)&b0, (void*)&W1, (void*)&b1,
                  (void*)&hidden, (void*)&xb16,
                  (void*)&h0A, (void*)&h0B, (void*)&h1A, (void*)&h1B,
                  (void*)&finals, (void*)&bar};
  hipLaunchCooperativeKernel((const void*)k_persist, dim3(256), dim3(512),
                             args, ldsBytes, stream);

  k_outproj<<<Bdim, 256, 0, stream>>>(finals + 2 * BH, Wout, bout, out);
}

// Round 3
// 11510.747 us; speedup vs baseline: 2.0582x; 2.0582x over previous
//
#include <hip/hip_runtime.h>
#include <hip/hip_bf16.h>
#include <cstdint>
#include <cstddef>

#define Bdim 256
#define Tdim 256
#define Idim 512
#define Hdim 1024
#define Odim 5
#define BH (Bdim * Hdim)

using short8 = __attribute__((ext_vector_type(8))) short;
using f32x4  = __attribute__((ext_vector_type(4))) float;

__device__ __forceinline__ short bf16_of(float f) {
  unsigned u = __builtin_bit_cast(unsigned, f);
  u += 0x7fffu + ((u >> 16) & 1u);
  return (short)(u >> 16);
}

__device__ __forceinline__ float sigmf(float x) {
  return 1.0f / (1.0f + __expf(-x));
}

// x fp32 [B][T][I] -> bf16 [T][B][I]
__global__ __launch_bounds__(256) void k_cvt_x(const float* __restrict__ src,
                                               short* __restrict__ dst) {
  int e = (blockIdx.x * 256 + threadIdx.x) * 8;
  int row = e >> 9;          // b*T + t
  int i0  = e & 511;
  int b = row >> 8, t = row & 255;
  float4 u = *reinterpret_cast<const float4*>(src + e);
  float4 v = *reinterpret_cast<const float4*>(src + e + 4);
  short8 o = {bf16_of(u.x), bf16_of(u.y), bf16_of(u.z), bf16_of(u.w),
              bf16_of(v.x), bf16_of(v.y), bf16_of(v.z), bf16_of(v.w)};
  *reinterpret_cast<short8*>(dst + (((t << 8) + b) << 9) + i0) = o;
}

__global__ __launch_bounds__(256) void k_init(const float* __restrict__ hidden,
    short* __restrict__ h0b, short* __restrict__ h1b) {
  int i = blockIdx.x * 256 + threadIdx.x;
  if (i < BH) {
    h0b[i] = bf16_of(hidden[i]);
    h1b[i] = bf16_of(hidden[2 * BH + i]);
  }
}

// Release/acquire grid barrier. CRITICAL: spin with RELAXED loads (no cache
// invalidate per poll); exactly ONE acquire (L2 inv) after the count is hit.
__device__ __forceinline__ void grid_barrier(unsigned* bar, unsigned target) {
  __syncthreads();
  if (threadIdx.x == 0) {
    // release: writes back this XCD's dirty h-lines to the coherence point
    __hip_atomic_fetch_add(bar, 1u, __ATOMIC_RELEASE, __HIP_MEMORY_SCOPE_AGENT);
    unsigned v;
    do {
      __builtin_amdgcn_s_sleep(8);
      v = __hip_atomic_load(bar, __ATOMIC_RELAXED, __HIP_MEMORY_SCOPE_AGENT);
    } while (v < target);
    // acquire: single L1/L2 invalidate so this round's remote h is visible
    (void)__hip_atomic_load(bar, __ATOMIC_ACQUIRE, __HIP_MEMORY_SCOPE_AGENT);
  }
  __syncthreads();
}

// Persistent weight-stationary LSTM.
// grid = 256 WGs x 512 threads. WG 0..127: layer0 (8 h-cols each);
// WG 128..255: layer1. Skewed pipeline: round r -> L0 step r, L1 step r-1.
__global__ __launch_bounds__(512, 1) void k_persist(
    const float* __restrict__ W0, const float* __restrict__ b0v,
    const float* __restrict__ W1, const float* __restrict__ b1v,
    const float* __restrict__ hidden,
    const short* __restrict__ xb,     // [T][B][I] bf16
    short* __restrict__ h0A, short* __restrict__ h0B,
    short* __restrict__ h1A, short* __restrict__ h1B,
    float* __restrict__ finals,       // [L][2][B][H] fp32 (in d_out)
    unsigned* __restrict__ bar) {
  extern __shared__ short lw[];       // [32][pitch] bf16 weight slice
  const int tid  = threadIdx.x;
  const int wg   = blockIdx.x;
  const bool isL0 = (wg < 128);
  const int slot  = isL0 ? wg : wg - 128;
  const int hcol0 = slot * 8;
  const int K     = isL0 ? (Hdim + Idim) : (2 * Hdim);
  const int pitch = K + 8;            // odd 16B-stride per row -> balanced banks
  const int layer = isL0 ? 0 : 1;
  const float* Wsrc = isL0 ? W0 : W1;
  const float* bsrc = isL0 ? b0v : b1v;

  // ---- stage weight slice into LDS (fp32 -> bf16), rows r = gate*8 + hcol ----
  for (int r = 0; r < 32; ++r) {
    const float* src = Wsrc + (size_t)((r >> 3) * Hdim + hcol0 + (r & 7)) * K;
    short* dst = lw + r * pitch;
    for (int k = tid; k < K; k += 512) dst[k] = bf16_of(src[k]);
  }

  const int lane = tid & 63;
  const int wv   = tid >> 6;          // wave 0..7 -> batch rows [wv*32, wv*32+32)
  const int col  = lane & 15;         // MFMA N-col / A-row index
  const int rg   = lane >> 4;

  // bias: n=0 -> gates f(col<8)/i(col>=8); n=1 -> g/o
  float biasv[2];
  #pragma unroll
  for (int n = 0; n < 2; ++n)
    biasv[n] = bsrc[(n * 2 + (col >= 8 ? 1 : 0)) * Hdim + hcol0 + (col & 7)];

  // c-state in registers (meaningful on lanes col<8); h-final kept for epilogue
  float creg[2][4], hfin[2][4];
  #pragma unroll
  for (int m = 0; m < 2; ++m)
    #pragma unroll
    for (int j = 0; j < 4; ++j) {
      int b = wv * 32 + m * 16 + rg * 4 + j;
      creg[m][j] = hidden[(layer * 2 + 1) * BH + b * Hdim + hcol0 + (col & 7)];
      hfin[m][j] = 0.f;
    }

  short* h0buf[2] = {h0A, h0B};
  short* h1buf[2] = {h1A, h1B};

  __syncthreads();

  const short* lb0 = lw + col * pitch;          // N-tile 0: gates f,i
  const short* lb1 = lw + (16 + col) * pitch;   // N-tile 1: gates g,o
  const int kl = rg * 8;

  for (int r = 0; r <= 256; ++r) {
    const bool active = isL0 ? (r < 256) : (r >= 1);
    if (active) {
      const int t = isL0 ? r : r - 1;
      // A rows: K[0,H) = own h(t-1); K[H,K) = x_t (L0) or h0(t) (L1)
      const short* Ah = isL0 ? h0buf[r & 1] : h1buf[(r + 1) & 1];
      const short* Ax = isL0 ? (xb + (size_t)t * (Bdim * Idim)) : h0buf[r & 1];
      short* hout = isL0 ? h0buf[(r + 1) & 1] : h1buf[r & 1];
      const int xstride = isL0 ? Idim : Hdim;

      f32x4 acc[2][2] = {};
      const short* ah0 = Ah + (wv * 32 + col) * Hdim;
      const short* ah1 = ah0 + 16 * Hdim;
      #pragma unroll 8
      for (int k0 = 0; k0 < Hdim; k0 += 32) {
        int k = k0 + kl;
        short8 a0  = *(const short8*)(ah0 + k);
        short8 a1  = *(const short8*)(ah1 + k);
        short8 bf0 = *(const short8*)(lb0 + k);
        short8 bf1 = *(const short8*)(lb1 + k);
        acc[0][0] = __builtin_amdgcn_mfma_f32_16x16x32_bf16(a0, bf0, acc[0][0], 0, 0, 0);
        acc[1][0] = __builtin_amdgcn_mfma_f32_16x16x32_bf16(a1, bf0, acc[1][0], 0, 0, 0);
        acc[0][1] = __builtin_amdgcn_mfma_f32_16x16x32_bf16(a0, bf1, acc[0][1], 0, 0, 0);
        acc[1][1] = __builtin_amdgcn_mfma_f32_16x16x32_bf16(a1, bf1, acc[1][1], 0, 0, 0);
      }
      const short* ax0 = Ax + (size_t)(wv * 32 + col) * xstride - Hdim;
      const short* ax1 = ax0 + 16 * xstride;
      #pragma unroll 8
      for (int k0 = Hdim; k0 < K; k0 += 32) {
        int k = k0 + kl;
        short8 a0  = *(const short8*)(ax0 + k);
        short8 a1  = *(const short8*)(ax1 + k);
        short8 bf0 = *(const short8*)(lb0 + k);
        short8 bf1 = *(const short8*)(lb1 + k);
        acc[0][0] = __builtin_amdgcn_mfma_f32_16x16x32_bf16(a0, bf0, acc[0][0], 0, 0, 0);
        acc[1][0] = __builtin_amdgcn_mfma_f32_16x16x32_bf16(a1, bf0, acc[1][0], 0, 0, 0);
        acc[0][1] = __builtin_amdgcn_mfma_f32_16x16x32_bf16(a0, bf1, acc[0][1], 0, 0, 0);
        acc[1][1] = __builtin_amdgcn_mfma_f32_16x16x32_bf16(a1, bf1, acc[1][1], 0, 0, 0);
      }
      // fused gates: D row = rg*4+j -> batch; col<8 lanes own h-col hcol0+col
      #pragma unroll
      for (int m = 0; m < 2; ++m) {
        #pragma unroll
        for (int j = 0; j < 4; ++j) {
          float fi  = acc[m][0][j] + biasv[0];
          float go  = acc[m][1][j] + biasv[1];
          float iv_ = __shfl_xor(fi, 8, 64);
          float ov_ = __shfl_xor(go, 8, 64);
          float fv = sigmf(fi), iv = sigmf(iv_);
          float gv = tanhf(go), ov = sigmf(ov_);
          float cn = fv * creg[m][j] + iv * gv;
          creg[m][j] = cn;
          float hn = ov * tanhf(cn);
          hfin[m][j] = hn;
          if (col < 8) {
            int b = wv * 32 + m * 16 + rg * 4 + j;
            hout[b * Hdim + hcol0 + col] = bf16_of(hn);
          }
        }
      }
    }
    if (r < 256) grid_barrier(bar, (unsigned)(r + 1) * 256u);
  }

  // epilogue: finals [L][2][B][H]
  if (col < 8) {
    #pragma unroll
    for (int m = 0; m < 2; ++m)
      #pragma unroll
      for (int j = 0; j < 4; ++j) {
        int b = wv * 32 + m * 16 + rg * 4 + j;
        finals[(layer * 2 + 0) * BH + b * Hdim + hcol0 + col] = hfin[m][j];
        finals[(layer * 2 + 1) * BH + b * Hdim + hcol0 + col] = creg[m][j];
      }
  }
}

__global__ __launch_bounds__(256) void k_outproj(const float* __restrict__ h1f,
    const float* __restrict__ Wout, const float* __restrict__ bout,
    float* __restrict__ out) {
  int b = blockIdx.x;
  int tid = threadIdx.x;
  float hv[4];
  #pragma unroll
  for (int j = 0; j < 4; ++j) hv[j] = h1f[b * Hdim + tid + j * 256];
  __shared__ float red[Odim][4];
  #pragma unroll
  for (int o = 0; o < Odim; ++o) {
    float p = 0.f;
    #pragma unroll
    for (int j = 0; j < 4; ++j) p += hv[j] * Wout[o * Hdim + tid + j * 256];
    #pragma unroll
    for (int s = 32; s > 0; s >>= 1) p += __shfl_down(p, s, 64);
    if ((tid & 63) == 0) red[o][tid >> 6] = p;
  }
  __syncthreads();
  if (tid < Odim)
    out[b * Odim + tid] = red[tid][0] + red[tid][1] + red[tid][2] + red[tid][3] + bout[tid];
}

extern "C" void kernel_launch(void* const* d_in, const int* in_sizes, int n_in,
                              void* d_out, int out_size, void* d_ws, size_t ws_size,
                              hipStream_t stream) {
  const float* x      = (const float*)d_in[0];
  const float* hidden = (const float*)d_in[1];
  const float* W0     = (const float*)d_in[2];
  const float* b0     = (const float*)d_in[3];
  const float* W1     = (const float*)d_in[4];
  const float* b1     = (const float*)d_in[5];
  const float* Wout   = (const float*)d_in[6];
  const float* bout   = (const float*)d_in[7];
  float* out = (float*)d_out;
  float* finals = out + Bdim * Odim;

  char* ws = (char*)d_ws;
  size_t off = 0;
  auto alloc = [&](size_t bytes) {
    void* p = ws + off;
    off += (bytes + 255) & ~(size_t)255;
    return p;
  };
  short* xb16 = (short*)alloc((size_t)Tdim * Bdim * Idim * 2);  // 67.1 MB
  short* h0A  = (short*)alloc((size_t)BH * 2);
  short* h0B  = (short*)alloc((size_t)BH * 2);
  short* h1A  = (short*)alloc((size_t)BH * 2);
  short* h1B  = (short*)alloc((size_t)BH * 2);
  unsigned* bar = (unsigned*)alloc(256);

  k_cvt_x<<<(Tdim * Bdim * Idim) / (256 * 8), 256, 0, stream>>>(x, xb16);
  k_init<<<BH / 256, 256, 0, stream>>>(hidden, h0A, h1A);
  hipMemsetAsync(bar, 0, sizeof(unsigned), stream);

  const int ldsBytes = 32 * (2 * Hdim + 8) * 2;  // 131584 (L1 slice, the max)
  hipFuncSetAttribute((const void*)k_persist,
                      hipFuncAttributeMaxDynamicSharedMemorySize, ldsBytes);
  void* args[] = {(void*)&W0, (void*)&b0, (void*)&W1, (void*)&b1,
                  (void*)&hidden, (void*)&xb16,
                  (void*)&h0A, (void*)&h0B, (void*)&h1A, (void*)&h1B,
                  (void*)&finals, (void*)&bar};
  hipLaunchCooperativeKernel((const void*)k_persist, dim3(256), dim3(512),
                             args, ldsBytes, stream);

  k_outproj<<<Bdim, 256, 0, stream>>>(finals + 2 * BH, Wout, bout, out);
}

// Round 4
// 11110.072 us; speedup vs baseline: 2.1324x; 1.0361x over previous
//
#include <hip/hip_runtime.h>
#include <hip/hip_bf16.h>
#include <cstdint>
#include <cstddef>

#define Bdim 256
#define Tdim 256
#define Idim 512
#define Hdim 1024
#define Odim 5
#define BH (Bdim * Hdim)

using short8 = __attribute__((ext_vector_type(8))) short;
using f32x4  = __attribute__((ext_vector_type(4))) float;

__device__ __forceinline__ short bf16_of(float f) {
  unsigned u = __builtin_bit_cast(unsigned, f);
  u += 0x7fffu + ((u >> 16) & 1u);
  return (short)(u >> 16);
}

__device__ __forceinline__ float sigmf(float x) {
  return 1.0f / (1.0f + __expf(-x));
}

// x fp32 [B][T][I] -> bf16 [T][B][I]
__global__ __launch_bounds__(256) void k_cvt_x(const float* __restrict__ src,
                                               short* __restrict__ dst) {
  int e = (blockIdx.x * 256 + threadIdx.x) * 8;
  int row = e >> 9;          // b*T + t
  int i0  = e & 511;
  int b = row >> 8, t = row & 255;
  float4 u = *reinterpret_cast<const float4*>(src + e);
  float4 v = *reinterpret_cast<const float4*>(src + e + 4);
  short8 o = {bf16_of(u.x), bf16_of(u.y), bf16_of(u.z), bf16_of(u.w),
              bf16_of(v.x), bf16_of(v.y), bf16_of(v.z), bf16_of(v.w)};
  *reinterpret_cast<short8*>(dst + (((t << 8) + b) << 9) + i0) = o;
}

__global__ __launch_bounds__(256) void k_init(const float* __restrict__ hidden,
    short* __restrict__ h0b, short* __restrict__ h1b) {
  int i = blockIdx.x * 256 + threadIdx.x;
  if (i < BH) {
    h0b[i] = bf16_of(hidden[i]);
    h1b[i] = bf16_of(hidden[2 * BH + i]);
  }
}

// ---- contention-free grid barrier: per-WG slot stores + one-wave poll ----
__device__ __forceinline__ void bar_arrive(unsigned* slots, unsigned val) {
  __syncthreads();   // all waves' h-stores at vmcnt(0) -> in L2
  if (threadIdx.x == 0)
    __hip_atomic_store(&slots[blockIdx.x], val, __ATOMIC_RELEASE,
                       __HIP_MEMORY_SCOPE_AGENT);  // wbL2 + store (no RMW)
}

__device__ __forceinline__ void bar_wait(unsigned* slots, unsigned val) {
  if (threadIdx.x < 64) {
    unsigned* p = slots + threadIdx.x * 4;
    for (;;) {
      unsigned v0 = __hip_atomic_load(p + 0, __ATOMIC_RELAXED, __HIP_MEMORY_SCOPE_AGENT);
      unsigned v1 = __hip_atomic_load(p + 1, __ATOMIC_RELAXED, __HIP_MEMORY_SCOPE_AGENT);
      unsigned v2 = __hip_atomic_load(p + 2, __ATOMIC_RELAXED, __HIP_MEMORY_SCOPE_AGENT);
      unsigned v3 = __hip_atomic_load(p + 3, __ATOMIC_RELAXED, __HIP_MEMORY_SCOPE_AGENT);
      bool ok = (v0 >= val) & (v1 >= val) & (v2 >= val) & (v3 >= val);
      if (__all(ok)) break;
      __builtin_amdgcn_s_sleep(1);
    }
    if (threadIdx.x == 0)   // single acquire: one L1/L2 invalidate per round
      (void)__hip_atomic_load(slots, __ATOMIC_ACQUIRE, __HIP_MEMORY_SCOPE_AGENT);
  }
  __syncthreads();
}

// 8-deep pipelined GEMM block: issue 16 global + 16 LDS loads, then 32 MFMA.
#define GEMM_BLOCKS(A0P, A1P, WK0, NBLK)                                       \
  for (int blk = 0; blk < (NBLK); ++blk) {                                     \
    short8 Ar0[8], Ar1[8], Br0[8], Br1[8];                                     \
    const int kb = blk * 256 + kl;                                             \
    _Pragma("unroll")                                                          \
    for (int u = 0; u < 8; ++u) {                                              \
      const int k = kb + u * 32;                                               \
      Ar0[u] = *(const short8*)((A0P) + k);                                    \
      Ar1[u] = *(const short8*)((A1P) + k);                                    \
      Br0[u] = *(const short8*)(lb0 + (WK0) + k);                              \
      Br1[u] = *(const short8*)(lb1 + (WK0) + k);                              \
    }                                                                          \
    _Pragma("unroll")                                                          \
    for (int u = 0; u < 8; ++u) {                                              \
      acc[0][0] = __builtin_amdgcn_mfma_f32_16x16x32_bf16(Ar0[u], Br0[u], acc[0][0], 0, 0, 0); \
      acc[1][0] = __builtin_amdgcn_mfma_f32_16x16x32_bf16(Ar1[u], Br0[u], acc[1][0], 0, 0, 0); \
      acc[0][1] = __builtin_amdgcn_mfma_f32_16x16x32_bf16(Ar0[u], Br1[u], acc[0][1], 0, 0, 0); \
      acc[1][1] = __builtin_amdgcn_mfma_f32_16x16x32_bf16(Ar1[u], Br1[u], acc[1][1], 0, 0, 0); \
    }                                                                          \
  }

// Persistent weight-stationary LSTM. 256 WGs x 512 thr; WG<128: L0, else L1.
// Skew: round r -> L0 step r, L1 step r-1. x-part GEMM runs BEFORE bar_wait.
__global__ __launch_bounds__(512, 1) void k_persist(
    const float* __restrict__ W0, const float* __restrict__ b0v,
    const float* __restrict__ W1, const float* __restrict__ b1v,
    const float* __restrict__ hidden,
    const short* __restrict__ xb,     // [T][B][I] bf16
    short* __restrict__ h0A, short* __restrict__ h0B,
    short* __restrict__ h1A, short* __restrict__ h1B,
    float* __restrict__ finals,       // [L][2][B][H] fp32 (in d_out)
    unsigned* __restrict__ slots) {
  extern __shared__ short lw[];       // [32][pitch] bf16 weight slice
  const int tid  = threadIdx.x;
  const int wg   = blockIdx.x;
  const bool isL0 = (wg < 128);
  const int slot  = isL0 ? wg : wg - 128;
  const int hcol0 = slot * 8;
  const int K     = isL0 ? (Hdim + Idim) : (2 * Hdim);
  const int pitch = K + 8;            // odd 16B row stride -> balanced banks
  const int layer = isL0 ? 0 : 1;
  const float* Wsrc = isL0 ? W0 : W1;
  const float* bsrc = isL0 ? b0v : b1v;

  // stage weight slice into LDS (fp32 -> bf16), rows r = gate*8 + hcol
  for (int r = 0; r < 32; ++r) {
    const float* src = Wsrc + (size_t)((r >> 3) * Hdim + hcol0 + (r & 7)) * K;
    short* dst = lw + r * pitch;
    for (int k = tid; k < K; k += 512) dst[k] = bf16_of(src[k]);
  }

  const int lane = tid & 63;
  const int wv   = tid >> 6;          // wave -> batch rows [wv*32, wv*32+32)
  const int col  = lane & 15;
  const int rg   = lane >> 4;
  const int kl   = rg * 8;
  const int row0 = wv * 32 + col;

  float biasv[2];
  #pragma unroll
  for (int n = 0; n < 2; ++n)
    biasv[n] = bsrc[(n * 2 + (col >= 8 ? 1 : 0)) * Hdim + hcol0 + (col & 7)];

  float creg[2][4], hfin[2][4];
  #pragma unroll
  for (int m = 0; m < 2; ++m)
    #pragma unroll
    for (int j = 0; j < 4; ++j) {
      int b = wv * 32 + m * 16 + rg * 4 + j;
      creg[m][j] = hidden[(layer * 2 + 1) * BH + b * Hdim + hcol0 + (col & 7)];
      hfin[m][j] = 0.f;
    }

  short* h0buf[2] = {h0A, h0B};
  short* h1buf[2] = {h1A, h1B};

  __syncthreads();

  const short* lb0 = lw + col * pitch;          // N-tile 0: gates f,i
  const short* lb1 = lw + (16 + col) * pitch;   // N-tile 1: gates g,o

  for (int r = 0; r <= 256; ++r) {
    const bool active = isL0 ? (r < 256) : (r >= 1);
    const int t = isL0 ? r : r - 1;
    f32x4 acc[2][2] = {};

    if (active && isL0) {
      // x-part (K in [1024,1536)) — static input, runs while others finish r-1
      const short* ax0 = xb + (size_t)t * (Bdim * Idim) + row0 * Idim;
      const short* ax1 = ax0 + 16 * Idim;
      GEMM_BLOCKS(ax0, ax1, Hdim, 2)
    }
    __builtin_amdgcn_sched_barrier(0);
    if (r > 0) bar_wait(slots, (unsigned)r);

    if (active) {
      const short* Ah = isL0 ? h0buf[r & 1] : h1buf[(r + 1) & 1];
      short* hout = isL0 ? h0buf[(r + 1) & 1] : h1buf[r & 1];
      const short* ah0 = Ah + row0 * Hdim;
      GEMM_BLOCKS(ah0, ah0 + 16 * Hdim, 0, 4)
      if (!isL0) {  // L1 x-part = h0(t), written by L0 in round r-1
        const short* axh = h0buf[r & 1] + row0 * Hdim;
        GEMM_BLOCKS(axh, axh + 16 * Hdim, Hdim, 4)
      }
      // fused gates: D row = rg*4+j -> batch; lanes col<8 own h-col hcol0+col
      #pragma unroll
      for (int m = 0; m < 2; ++m) {
        #pragma unroll
        for (int j = 0; j < 4; ++j) {
          float fi  = acc[m][0][j] + biasv[0];
          float go  = acc[m][1][j] + biasv[1];
          float iv_ = __shfl_xor(fi, 8, 64);
          float ov_ = __shfl_xor(go, 8, 64);
          float fv = sigmf(fi), iv = sigmf(iv_);
          float gv = tanhf(go), ov = sigmf(ov_);
          float cn = fv * creg[m][j] + iv * gv;
          creg[m][j] = cn;
          float hn = ov * tanhf(cn);
          hfin[m][j] = hn;
          if (col < 8) {
            int b = wv * 32 + m * 16 + rg * 4 + j;
            hout[b * Hdim + hcol0 + col] = bf16_of(hn);
          }
        }
      }
    }
    if (r < 256) bar_arrive(slots, (unsigned)(r + 1));
  }

  // epilogue: finals [L][2][B][H]
  if (col < 8) {
    #pragma unroll
    for (int m = 0; m < 2; ++m)
      #pragma unroll
      for (int j = 0; j < 4; ++j) {
        int b = wv * 32 + m * 16 + rg * 4 + j;
        finals[(layer * 2 + 0) * BH + b * Hdim + hcol0 + col] = hfin[m][j];
        finals[(layer * 2 + 1) * BH + b * Hdim + hcol0 + col] = creg[m][j];
      }
  }
}

__global__ __launch_bounds__(256) void k_outproj(const float* __restrict__ h1f,
    const float* __restrict__ Wout, const float* __restrict__ bout,
    float* __restrict__ out) {
  int b = blockIdx.x;
  int tid = threadIdx.x;
  float hv[4];
  #pragma unroll
  for (int j = 0; j < 4; ++j) hv[j] = h1f[b * Hdim + tid + j * 256];
  __shared__ float red[Odim][4];
  #pragma unroll
  for (int o = 0; o < Odim; ++o) {
    float p = 0.f;
    #pragma unroll
    for (int j = 0; j < 4; ++j) p += hv[j] * Wout[o * Hdim + tid + j * 256];
    #pragma unroll
    for (int s = 32; s > 0; s >>= 1) p += __shfl_down(p, s, 64);
    if ((tid & 63) == 0) red[o][tid >> 6] = p;
  }
  __syncthreads();
  if (tid < Odim)
    out[b * Odim + tid] = red[tid][0] + red[tid][1] + red[tid][2] + red[tid][3] + bout[tid];
}

extern "C" void kernel_launch(void* const* d_in, const int* in_sizes, int n_in,
                              void* d_out, int out_size, void* d_ws, size_t ws_size,
                              hipStream_t stream) {
  const float* x      = (const float*)d_in[0];
  const float* hidden = (const float*)d_in[1];
  const float* W0     = (const float*)d_in[2];
  const float* b0     = (const float*)d_in[3];
  const float* W1     = (const float*)d_in[4];
  const float* b1     = (const float*)d_in[5];
  const float* Wout   = (const float*)d_in[6];
  const float* bout   = (const float*)d_in[7];
  float* out = (float*)d_out;
  float* finals = out + Bdim * Odim;

  char* ws = (char*)d_ws;
  size_t off = 0;
  auto alloc = [&](size_t bytes) {
    void* p = ws + off;
    off += (bytes + 255) & ~(size_t)255;
    return p;
  };
  short* xb16 = (short*)alloc((size_t)Tdim * Bdim * Idim * 2);  // 67.1 MB
  short* h0A  = (short*)alloc((size_t)BH * 2);
  short* h0B  = (short*)alloc((size_t)BH * 2);
  short* h1A  = (short*)alloc((size_t)BH * 2);
  short* h1B  = (short*)alloc((size_t)BH * 2);
  unsigned* slots = (unsigned*)alloc(256 * sizeof(unsigned));

  k_cvt_x<<<(Tdim * Bdim * Idim) / (256 * 8), 256, 0, stream>>>(x, xb16);
  k_init<<<BH / 256, 256, 0, stream>>>(hidden, h0A, h1A);
  hipMemsetAsync(slots, 0, 256 * sizeof(unsigned), stream);  // reset every launch!

  const int ldsBytes = 32 * (2 * Hdim + 8) * 2;  // 131584 (L1 slice, the max)
  hipFuncSetAttribute((const void*)k_persist,
                      hipFuncAttributeMaxDynamicSharedMemorySize, ldsBytes);
  void* args[] = {(void*)&W0, (void*)&b0, (void*)&W1, (void*)&b1,
                  (void*)&hidden, (void*)&xb16,
                  (void*)&h0A, (void*)&h0B, (void*)&h1A, (void*)&h1B,
                  (void*)&finals, (void*)&slots};
  hipLaunchCooperativeKernel((const void*)k_persist, dim3(256), dim3(512),
                             args, ldsBytes, stream);

  k_outproj<<<Bdim, 256, 0, stream>>>(finals + 2 * BH, Wout, bout, out);
}

// Round 5
// 8661.396 us; speedup vs baseline: 2.7353x; 1.2827x over previous
//
#include <hip/hip_runtime.h>
#include <hip/hip_bf16.h>
#include <cstdint>
#include <cstddef>

#define Bdim 256
#define Tdim 256
#define Idim 512
#define Hdim 1024
#define Odim 5
#define BH (Bdim * Hdim)

using short8 = __attribute__((ext_vector_type(8))) short;
using f32x4  = __attribute__((ext_vector_type(4))) float;
typedef unsigned long long u64;

__device__ __forceinline__ short bf16_of(float f) {
  unsigned u = __builtin_bit_cast(unsigned, f);
  u += 0x7fffu + ((u >> 16) & 1u);
  return (short)(u >> 16);
}

__device__ __forceinline__ float sigmf(float x) {
  return 1.0f / (1.0f + __expf(-x));
}

// initial h states -> slot 0 of each sequence buffer
__global__ __launch_bounds__(256) void k_init(const float* __restrict__ hidden,
    short* __restrict__ h0s0, short* __restrict__ h1s0) {
  int i = blockIdx.x * 256 + threadIdx.x;
  if (i < BH) {
    h0s0[i] = bf16_of(hidden[i]);
    h1s0[i] = bf16_of(hidden[2 * BH + i]);
  }
}

// arrive: relaxed agent slot store (atomics execute at MALL; no wbL2).
// __syncthreads drains vmcnt(0) per wave -> all sc1 h-stores are at MALL first.
__device__ __forceinline__ void bar_arrive(unsigned* slots, unsigned val) {
  __syncthreads();
  if (threadIdx.x == 0)
    __hip_atomic_store(&slots[blockIdx.x], val, __ATOMIC_RELAXED,
                       __HIP_MEMORY_SCOPE_AGENT);
}

// poll only; caller does (optional inv +) __syncthreads afterwards
__device__ __forceinline__ void bar_poll(unsigned* slots, unsigned val) {
  if (threadIdx.x < 64) {
    unsigned* p = slots + threadIdx.x * 4;
    for (;;) {
      unsigned v0 = __hip_atomic_load(p + 0, __ATOMIC_RELAXED, __HIP_MEMORY_SCOPE_AGENT);
      unsigned v1 = __hip_atomic_load(p + 1, __ATOMIC_RELAXED, __HIP_MEMORY_SCOPE_AGENT);
      unsigned v2 = __hip_atomic_load(p + 2, __ATOMIC_RELAXED, __HIP_MEMORY_SCOPE_AGENT);
      unsigned v3 = __hip_atomic_load(p + 3, __ATOMIC_RELAXED, __HIP_MEMORY_SCOPE_AGENT);
      bool ok = (v0 >= val) & (v1 >= val) & (v2 >= val) & (v3 >= val);
      if (__all(ok)) break;
      __builtin_amdgcn_s_sleep(1);
    }
  }
}

// bf16 GEMM block: 8-deep (16 global + 16 LDS loads, then 32 MFMA). k absolute.
#define GEMM_H(A0P, A1P, K0, NBLK)                                             \
  for (int blk = 0; blk < (NBLK); ++blk) {                                     \
    short8 Ar0[8], Ar1[8], Br0[8], Br1[8];                                     \
    const int kb = (K0) + blk * 256 + kl;                                      \
    _Pragma("unroll")                                                          \
    for (int u = 0; u < 8; ++u) {                                              \
      const int k = kb + u * 32;                                               \
      Ar0[u] = *(const short8*)((A0P) + k);                                    \
      Ar1[u] = *(const short8*)((A1P) + k);                                    \
      Br0[u] = *(const short8*)(lb0 + k);                                      \
      Br1[u] = *(const short8*)(lb1 + k);                                      \
    }                                                                          \
    _Pragma("unroll")                                                          \
    for (int u = 0; u < 8; ++u) {                                              \
      acc[0][0] = __builtin_amdgcn_mfma_f32_16x16x32_bf16(Ar0[u], Br0[u], acc[0][0], 0, 0, 0); \
      acc[1][0] = __builtin_amdgcn_mfma_f32_16x16x32_bf16(Ar1[u], Br0[u], acc[1][0], 0, 0, 0); \
      acc[0][1] = __builtin_amdgcn_mfma_f32_16x16x32_bf16(Ar0[u], Br1[u], acc[0][1], 0, 0, 0); \
      acc[1][1] = __builtin_amdgcn_mfma_f32_16x16x32_bf16(Ar1[u], Br1[u], acc[1][1], 0, 0, 0); \
    }                                                                          \
  }

// fp32 x-part (k in [1024,1536)): 4-deep, load fp32 + convert to bf16.
#define GEMM_X(XF0, XF1)                                                       \
  for (int blk = 0; blk < 4; ++blk) {                                          \
    f32x4 U0[4][2], U1[4][2]; short8 Bx0[4], Bx1[4];                           \
    const int kb = Hdim + blk * 128 + kl;                                      \
    _Pragma("unroll")                                                          \
    for (int u = 0; u < 4; ++u) {                                              \
      const int k = kb + u * 32;                                               \
      U0[u][0] = *(const f32x4*)((XF0) + k);                                   \
      U0[u][1] = *(const f32x4*)((XF0) + k + 4);                               \
      U1[u][0] = *(const f32x4*)((XF1) + k);                                   \
      U1[u][1] = *(const f32x4*)((XF1) + k + 4);                               \
      Bx0[u] = *(const short8*)(lb0 + k);                                      \
      Bx1[u] = *(const short8*)(lb1 + k);                                      \
    }                                                                          \
    _Pragma("unroll")                                                          \
    for (int u = 0; u < 4; ++u) {                                              \
      short8 a0 = {bf16_of(U0[u][0][0]), bf16_of(U0[u][0][1]), bf16_of(U0[u][0][2]), bf16_of(U0[u][0][3]), \
                   bf16_of(U0[u][1][0]), bf16_of(U0[u][1][1]), bf16_of(U0[u][1][2]), bf16_of(U0[u][1][3])}; \
      short8 a1 = {bf16_of(U1[u][0][0]), bf16_of(U1[u][0][1]), bf16_of(U1[u][0][2]), bf16_of(U1[u][0][3]), \
                   bf16_of(U1[u][1][0]), bf16_of(U1[u][1][1]), bf16_of(U1[u][1][2]), bf16_of(U1[u][1][3])}; \
      acc[0][0] = __builtin_amdgcn_mfma_f32_16x16x32_bf16(a0, Bx0[u], acc[0][0], 0, 0, 0); \
      acc[1][0] = __builtin_amdgcn_mfma_f32_16x16x32_bf16(a1, Bx0[u], acc[1][0], 0, 0, 0); \
      acc[0][1] = __builtin_amdgcn_mfma_f32_16x16x32_bf16(a0, Bx1[u], acc[0][1], 0, 0, 0); \
      acc[1][1] = __builtin_amdgcn_mfma_f32_16x16x32_bf16(a1, Bx1[u], acc[1][1], 0, 0, 0); \
    }                                                                          \
  }

// Persistent weight-stationary LSTM; write-once h-sequence buffers.
// 256 WGs x 512 thr; WG<128: L0, else L1. Round r: L0 step r, L1 step r-1.
__global__ __launch_bounds__(512, 1) void k_persist(
    const float* __restrict__ W0, const float* __restrict__ b0v,
    const float* __restrict__ W1, const float* __restrict__ b1v,
    const float* __restrict__ hidden,
    const float* __restrict__ x,      // fp32 [B][T][I]
    short* __restrict__ h0seq,        // [D][B][H] bf16
    short* __restrict__ h1seq,        // [D][B][H] bf16
    float* __restrict__ finals,       // [L][2][B][H] fp32 (in d_out)
    unsigned* __restrict__ slots, int D) {
  extern __shared__ short lw[];       // [32][pitch] bf16 weight slice
  const int tid  = threadIdx.x;
  const int wg   = blockIdx.x;
  const bool isL0 = (wg < 128);
  const int slot  = isL0 ? wg : wg - 128;
  const int hcol0 = slot * 8;
  const int K     = isL0 ? (Hdim + Idim) : (2 * Hdim);
  const int pitch = K + 8;            // odd 16B row stride -> balanced banks
  const int layer = isL0 ? 0 : 1;
  const float* Wsrc = isL0 ? W0 : W1;
  const float* bsrc = isL0 ? b0v : b1v;

  // stage weight slice into LDS (fp32 -> bf16), rows r = gate*8 + hcol
  for (int r = 0; r < 32; ++r) {
    const float* src = Wsrc + (size_t)((r >> 3) * Hdim + hcol0 + (r & 7)) * K;
    short* dst = lw + r * pitch;
    for (int k = tid; k < K; k += 512) dst[k] = bf16_of(src[k]);
  }

  const int lane = tid & 63;
  const int wv   = tid >> 6;          // wave -> batch rows [wv*32, wv*32+32)
  const int col  = lane & 15;
  const int rg   = lane >> 4;
  const int kl   = rg * 8;
  const int row0 = wv * 32 + col;

  float biasv[2];
  #pragma unroll
  for (int n = 0; n < 2; ++n)
    biasv[n] = bsrc[(n * 2 + (col >= 8 ? 1 : 0)) * Hdim + hcol0 + (col & 7)];

  float creg[2][4], hfin[2][4];
  #pragma unroll
  for (int m = 0; m < 2; ++m)
    #pragma unroll
    for (int j = 0; j < 4; ++j) {
      int b = wv * 32 + m * 16 + rg * 4 + j;
      creg[m][j] = hidden[(layer * 2 + 1) * BH + b * Hdim + hcol0 + (col & 7)];
      hfin[m][j] = 0.f;
    }

  // launch-start acquire: one L2/L1 inv per WG per LAUNCH (replay staleness)
  if (tid == 0)
    (void)__hip_atomic_load(slots, __ATOMIC_ACQUIRE, __HIP_MEMORY_SCOPE_AGENT);
  __syncthreads();

  const short* lb0 = lw + col * pitch;          // N-tile 0: gates f,i
  const short* lb1 = lw + (16 + col) * pitch;   // N-tile 1: gates g,o

  int i_cur = 0, i_prev = 0;                    // r % D, (r-1) % D
  for (int r = 0; r <= 256; ++r) {
    const bool active = isL0 ? (r < 256) : (r >= 1);
    const int t = isL0 ? r : r - 1;
    const int i_next = (i_cur + 1 == D) ? 0 : i_cur + 1;
    f32x4 acc[2][2] = {};

    if (active && isL0) {
      // x-part (static fp32 input) runs while other WGs finish round r-1
      const float* xf0 = x + (size_t)(row0 * Tdim + t) * Idim - Hdim;
      const float* xf1 = x + (size_t)((row0 + 16) * Tdim + t) * Idim - Hdim;
      GEMM_X(xf0, xf1)
    }
    __builtin_amdgcn_sched_barrier(0);
    if (r > 0) {
      bar_poll(slots, (unsigned)r);
      // wrap inv: once every D rounds, kill clean stale copies of recycled slots
      if (tid == 0 && i_cur == 0)
        (void)__hip_atomic_load(slots, __ATOMIC_ACQUIRE, __HIP_MEMORY_SCOPE_AGENT);
      __syncthreads();
    }

    if (active) {
      // h-part A rows (normal cached loads; write-once addresses => coherent)
      const short* Ah = (isL0 ? h0seq + (size_t)i_cur * BH
                               : h1seq + (size_t)i_prev * BH) + row0 * Hdim;
      GEMM_H(Ah, Ah + 16 * Hdim, 0, 4)
      if (!isL0) {  // L1 x-part = h0(t) = h0seq[i_cur]
        const short* Ax = h0seq + (size_t)i_cur * BH + row0 * Hdim - Hdim;
        GEMM_H(Ax, Ax + 16 * Hdim, Hdim, 4)
      }
      short* hout = isL0 ? h0seq + (size_t)i_next * BH
                         : h1seq + (size_t)i_cur * BH;
      // fused gates: D row = rg*4+j -> batch; lanes col<8 own h-col hcol0+col
      #pragma unroll
      for (int m = 0; m < 2; ++m) {
        #pragma unroll
        for (int j = 0; j < 4; ++j) {
          float fi  = acc[m][0][j] + biasv[0];
          float go  = acc[m][1][j] + biasv[1];
          float iv_ = __shfl_xor(fi, 8, 64);
          float ov_ = __shfl_xor(go, 8, 64);
          float fv = sigmf(fi), iv = sigmf(iv_);
          float gv = tanhf(go), ov = sigmf(ov_);
          float cn = fv * creg[m][j] + iv * gv;
          creg[m][j] = cn;
          float hn = ov * tanhf(cn);
          hfin[m][j] = hn;
          // pack 4 consecutive h-cols into one 8B agent-scope (MALL) store
          unsigned hv = (unsigned)(unsigned short)bf16_of(hn);
          unsigned p1 = hv | ((unsigned)__shfl_xor((int)hv, 1, 64) << 16);
          u64 p2 = (u64)p1 | ((u64)(unsigned)__shfl_xor((int)p1, 2, 64) << 32);
          if ((col & 3) == 0 && col < 8) {
            int b = wv * 32 + m * 16 + rg * 4 + j;
            __hip_atomic_store((u64*)(hout + b * Hdim + hcol0 + col), p2,
                               __ATOMIC_RELAXED, __HIP_MEMORY_SCOPE_AGENT);
          }
        }
      }
    }
    if (r < 256) bar_arrive(slots, (unsigned)(r + 1));
    i_prev = i_cur; i_cur = i_next;
  }

  // epilogue: finals [L][2][B][H]
  if (col < 8) {
    #pragma unroll
    for (int m = 0; m < 2; ++m)
      #pragma unroll
      for (int j = 0; j < 4; ++j) {
        int b = wv * 32 + m * 16 + rg * 4 + j;
        finals[(layer * 2 + 0) * BH + b * Hdim + hcol0 + col] = hfin[m][j];
        finals[(layer * 2 + 1) * BH + b * Hdim + hcol0 + col] = creg[m][j];
      }
  }
}

__global__ __launch_bounds__(256) void k_outproj(const float* __restrict__ h1f,
    const float* __restrict__ Wout, const float* __restrict__ bout,
    float* __restrict__ out) {
  int b = blockIdx.x;
  int tid = threadIdx.x;
  float hv[4];
  #pragma unroll
  for (int j = 0; j < 4; ++j) hv[j] = h1f[b * Hdim + tid + j * 256];
  __shared__ float red[Odim][4];
  #pragma unroll
  for (int o = 0; o < Odim; ++o) {
    float p = 0.f;
    #pragma unroll
    for (int j = 0; j < 4; ++j) p += hv[j] * Wout[o * Hdim + tid + j * 256];
    #pragma unroll
    for (int s = 32; s > 0; s >>= 1) p += __shfl_down(p, s, 64);
    if ((tid & 63) == 0) red[o][tid >> 6] = p;
  }
  __syncthreads();
  if (tid < Odim)
    out[b * Odim + tid] = red[tid][0] + red[tid][1] + red[tid][2] + red[tid][3] + bout[tid];
}

extern "C" void kernel_launch(void* const* d_in, const int* in_sizes, int n_in,
                              void* d_out, int out_size, void* d_ws, size_t ws_size,
                              hipStream_t stream) {
  const float* x      = (const float*)d_in[0];
  const float* hidden = (const float*)d_in[1];
  const float* W0     = (const float*)d_in[2];
  const float* b0     = (const float*)d_in[3];
  const float* W1     = (const float*)d_in[4];
  const float* b1     = (const float*)d_in[5];
  const float* Wout   = (const float*)d_in[6];
  const float* bout   = (const float*)d_in[7];
  float* out = (float*)d_out;
  float* finals = out + Bdim * Odim;

  char* ws = (char*)d_ws;
  size_t off = 0;
  auto alloc = [&](size_t bytes) {
    void* p = ws + off;
    off += (bytes + 255) & ~(size_t)255;
    return p;
  };
  unsigned* slots = (unsigned*)alloc(256 * sizeof(unsigned));
  const size_t seqSlotBytes = (size_t)BH * 2;                  // 0.5 MB
  size_t avail = (ws_size > off) ? (ws_size - off - 512) : 0;
  int D = (int)(avail / (2 * seqSlotBytes));
  if (D > 257) D = 257;
  if (D < 2) D = 2;  // ws guaranteed larger in practice (>=68MB used before)
  short* h0seq = (short*)alloc((size_t)D * seqSlotBytes);
  short* h1seq = (short*)alloc((size_t)D * seqSlotBytes);

  k_init<<<BH / 256, 256, 0, stream>>>(hidden, h0seq, h1seq);
  hipMemsetAsync(slots, 0, 256 * sizeof(unsigned), stream);  // reset every launch

  const int ldsBytes = 32 * (2 * Hdim + 8) * 2;  // 131584 (L1 slice, the max)
  hipFuncSetAttribute((const void*)k_persist,
                      hipFuncAttributeMaxDynamicSharedMemorySize, ldsBytes);
  void* args[] = {(void*)&W0, (void*)&b0, (void*)&W1, (void*)&b1,
                  (void*)&hidden, (void*)&x,
                  (void*)&h0seq, (void*)&h1seq,
                  (void*)&finals, (void*)&slots, (void*)&D};
  hipLaunchCooperativeKernel((const void*)k_persist, dim3(256), dim3(512),
                             args, ldsBytes, stream);

  k_outproj<<<Bdim, 256, 0, stream>>>(finals + 2 * BH, Wout, bout, out);
}

// Round 6
// 8248.618 us; speedup vs baseline: 2.8722x; 1.0500x over previous
//
#include <hip/hip_runtime.h>
#include <hip/hip_bf16.h>
#include <cstdint>
#include <cstddef>

#define Bdim 256
#define Tdim 256
#define Idim 512
#define Hdim 1024
#define Odim 5
#define BH (Bdim * Hdim)

using short8 = __attribute__((ext_vector_type(8))) short;
using f32x4  = __attribute__((ext_vector_type(4))) float;
typedef unsigned long long u64;

__device__ __forceinline__ short bf16_of(float f) {
  unsigned u = __builtin_bit_cast(unsigned, f);
  u += 0x7fffu + ((u >> 16) & 1u);
  return (short)(u >> 16);
}

__device__ __forceinline__ float sigmf(float x) {
  return 1.0f / (1.0f + __expf(-x));
}

// initial h states -> slot 0 of each sequence buffer
__global__ __launch_bounds__(256) void k_init(const float* __restrict__ hidden,
    short* __restrict__ h0s0, short* __restrict__ h1s0) {
  int i = blockIdx.x * 256 + threadIdx.x;
  if (i < BH) {
    h0s0[i] = bf16_of(hidden[i]);
    h1s0[i] = bf16_of(hidden[2 * BH + i]);
  }
}

// ---- split-group barrier: 2 layer-groups x 8 virtual-group counters ----
// ctr layout: [16][32] uints; counter c at ctr[c*32]. c = group*8 + (wg&7).
// arrive: one relaxed agent RMW (executes at MALL; h-stores already drained
// to MALL by __syncthreads' vmcnt(0) before the add issues).
__device__ __forceinline__ void ctr_arrive(unsigned* ctr, int c) {
  __builtin_amdgcn_sched_barrier(0);
  __syncthreads();
  if (threadIdx.x == 0)
    __hip_atomic_fetch_add(&ctr[c * 32], 1u, __ATOMIC_RELAXED,
                           __HIP_MEMORY_SCOPE_AGENT);
}

// poll: group0 counters (0..7) >= tg0 AND group1 counters (8..15) >= tg1.
// tgt==0 -> trivially satisfied. Only wave 0 polls; 8-16 relaxed loads/iter.
__device__ __forceinline__ void ctr_poll2(unsigned* ctr, unsigned tg0, unsigned tg1) {
  if (threadIdx.x < 64) {
    const int lane = threadIdx.x;
    const unsigned tgt = (lane < 8) ? tg0 : (lane < 16 ? tg1 : 0u);
    unsigned* p = ctr + (lane < 16 ? lane : 0) * 32;
    for (;;) {
      bool ok = true;
      if (tgt) {
        unsigned v = __hip_atomic_load(p, __ATOMIC_RELAXED, __HIP_MEMORY_SCOPE_AGENT);
        ok = (v >= tgt);
      }
      if (__all(ok)) break;
      __builtin_amdgcn_s_sleep(1);
    }
  }
}

// bf16 GEMM block: 8-deep (16 global + 16 LDS loads, then 32 MFMA). k absolute.
#define GEMM_H(A0P, A1P, K0, NBLK)                                             \
  for (int blk = 0; blk < (NBLK); ++blk) {                                     \
    short8 Ar0[8], Ar1[8], Br0[8], Br1[8];                                     \
    const int kb = (K0) + blk * 256 + kl;                                      \
    _Pragma("unroll")                                                          \
    for (int u = 0; u < 8; ++u) {                                              \
      const int k = kb + u * 32;                                               \
      Ar0[u] = *(const short8*)((A0P) + k);                                    \
      Ar1[u] = *(const short8*)((A1P) + k);                                    \
      Br0[u] = *(const short8*)(lb0 + k);                                      \
      Br1[u] = *(const short8*)(lb1 + k);                                      \
    }                                                                          \
    _Pragma("unroll")                                                          \
    for (int u = 0; u < 8; ++u) {                                              \
      acc[0][0] = __builtin_amdgcn_mfma_f32_16x16x32_bf16(Ar0[u], Br0[u], acc[0][0], 0, 0, 0); \
      acc[1][0] = __builtin_amdgcn_mfma_f32_16x16x32_bf16(Ar1[u], Br0[u], acc[1][0], 0, 0, 0); \
      acc[0][1] = __builtin_amdgcn_mfma_f32_16x16x32_bf16(Ar0[u], Br1[u], acc[0][1], 0, 0, 0); \
      acc[1][1] = __builtin_amdgcn_mfma_f32_16x16x32_bf16(Ar1[u], Br1[u], acc[1][1], 0, 0, 0); \
    }                                                                          \
  }

// fp32 x-part (k in [1024,1536)): 4-deep, load fp32 + convert to bf16.
#define GEMM_X(XF0, XF1)                                                       \
  for (int blk = 0; blk < 4; ++blk) {                                          \
    f32x4 U0[4][2], U1[4][2]; short8 Bx0[4], Bx1[4];                           \
    const int kb = Hdim + blk * 128 + kl;                                      \
    _Pragma("unroll")                                                          \
    for (int u = 0; u < 4; ++u) {                                              \
      const int k = kb + u * 32;                                               \
      U0[u][0] = *(const f32x4*)((XF0) + k);                                   \
      U0[u][1] = *(const f32x4*)((XF0) + k + 4);                               \
      U1[u][0] = *(const f32x4*)((XF1) + k);                                   \
      U1[u][1] = *(const f32x4*)((XF1) + k + 4);                               \
      Bx0[u] = *(const short8*)(lb0 + k);                                      \
      Bx1[u] = *(const short8*)(lb1 + k);                                      \
    }                                                                          \
    _Pragma("unroll")                                                          \
    for (int u = 0; u < 4; ++u) {                                              \
      short8 a0 = {bf16_of(U0[u][0][0]), bf16_of(U0[u][0][1]), bf16_of(U0[u][0][2]), bf16_of(U0[u][0][3]), \
                   bf16_of(U0[u][1][0]), bf16_of(U0[u][1][1]), bf16_of(U0[u][1][2]), bf16_of(U0[u][1][3])}; \
      short8 a1 = {bf16_of(U1[u][0][0]), bf16_of(U1[u][0][1]), bf16_of(U1[u][0][2]), bf16_of(U1[u][0][3]), \
                   bf16_of(U1[u][1][0]), bf16_of(U1[u][1][1]), bf16_of(U1[u][1][2]), bf16_of(U1[u][1][3])}; \
      acc[0][0] = __builtin_amdgcn_mfma_f32_16x16x32_bf16(a0, Bx0[u], acc[0][0], 0, 0, 0); \
      acc[1][0] = __builtin_amdgcn_mfma_f32_16x16x32_bf16(a1, Bx0[u], acc[1][0], 0, 0, 0); \
      acc[0][1] = __builtin_amdgcn_mfma_f32_16x16x32_bf16(a0, Bx1[u], acc[0][1], 0, 0, 0); \
      acc[1][1] = __builtin_amdgcn_mfma_f32_16x16x32_bf16(a1, Bx1[u], acc[1][1], 0, 0, 0); \
    }                                                                          \
  }

// Persistent weight-stationary LSTM; write-once h-sequence buffers; split
// per-layer barrier domains. Round r == timestep r for BOTH layers:
//   L0: reads h0seq[r%D], writes h0seq[(r+1)%D]   (waits ctrL0 >= 16r)
//   L1: reads h0seq[(r+1)%D] + h1seq[r%D], writes h1seq[(r+1)%D]
//       (waits ctrL0 >= 16(r+1) AND ctrL1 >= 16r)
// L0 free-runs ahead (throttled to <= D-4 rounds via lagged ctrL1 check).
__global__ __launch_bounds__(512, 1) void k_persist(
    const float* __restrict__ W0, const float* __restrict__ b0v,
    const float* __restrict__ W1, const float* __restrict__ b1v,
    const float* __restrict__ hidden,
    const float* __restrict__ x,      // fp32 [B][T][I]
    short* __restrict__ h0seq,        // [D][B][H] bf16
    short* __restrict__ h1seq,        // [D][B][H] bf16
    float* __restrict__ finals,       // [L][2][B][H] fp32 (in d_out)
    unsigned* __restrict__ ctr, int D) {
  extern __shared__ short lw[];       // [32][pitch] bf16 weight slice
  const int tid  = threadIdx.x;
  const int wg   = blockIdx.x;
  const bool isL0 = (wg < 128);
  const int slot  = isL0 ? wg : wg - 128;
  const int hcol0 = slot * 8;
  const int K     = isL0 ? (Hdim + Idim) : (2 * Hdim);
  const int pitch = K + 8;            // odd 16B row stride -> balanced banks
  const int layer = isL0 ? 0 : 1;
  const int myc   = layer * 8 + (wg & 7);
  const int lead  = D - 4;            // max L0 run-ahead
  const float* Wsrc = isL0 ? W0 : W1;
  const float* bsrc = isL0 ? b0v : b1v;

  // stage weight slice into LDS (fp32 -> bf16), rows r = gate*8 + hcol
  for (int r = 0; r < 32; ++r) {
    const float* src = Wsrc + (size_t)((r >> 3) * Hdim + hcol0 + (r & 7)) * K;
    short* dst = lw + r * pitch;
    for (int k = tid; k < K; k += 512) dst[k] = bf16_of(src[k]);
  }

  const int lane = tid & 63;
  const int wv   = tid >> 6;          // wave -> batch rows [wv*32, wv*32+32)
  const int col  = lane & 15;
  const int rg   = lane >> 4;
  const int kl   = rg * 8;
  const int row0 = wv * 32 + col;

  float biasv[2];
  #pragma unroll
  for (int n = 0; n < 2; ++n)
    biasv[n] = bsrc[(n * 2 + (col >= 8 ? 1 : 0)) * Hdim + hcol0 + (col & 7)];

  float creg[2][4], hfin[2][4];
  #pragma unroll
  for (int m = 0; m < 2; ++m)
    #pragma unroll
    for (int j = 0; j < 4; ++j) {
      int b = wv * 32 + m * 16 + rg * 4 + j;
      creg[m][j] = hidden[(layer * 2 + 1) * BH + b * Hdim + hcol0 + (col & 7)];
      hfin[m][j] = 0.f;
    }

  // launch-start acquire: one L2/L1 inv per WG per LAUNCH (replay staleness)
  if (tid == 0)
    (void)__hip_atomic_load(ctr, __ATOMIC_ACQUIRE, __HIP_MEMORY_SCOPE_AGENT);
  __syncthreads();

  const short* lb0 = lw + col * pitch;          // N-tile 0: gates f,i
  const short* lb1 = lw + (16 + col) * pitch;   // N-tile 1: gates g,o

  int i_cur = 0;                                // r % D
  for (int r = 0; r < 256; ++r) {
    const int i_next = (i_cur + 1 == D) ? 0 : i_cur + 1;
    f32x4 acc[2][2] = {};
    short* hout;

    if (isL0) {
      // x-part (static fp32 input, no dependency) hides the poll latency
      const float* xf0 = x + (size_t)(row0 * Tdim + r) * Idim - Hdim;
      const float* xf1 = x + (size_t)((row0 + 16) * Tdim + r) * Idim - Hdim;
      GEMM_X(xf0, xf1)
      __builtin_amdgcn_sched_barrier(0);
      unsigned tg1 = (r > lead) ? 16u * (unsigned)(r - lead) : 0u;  // throttle
      if (r > 0 || tg1) ctr_poll2(ctr, 16u * (unsigned)r, tg1);
      if (tid == 0 && D < 257 && r >= D - 1)   // recycled-slot staleness guard
        (void)__hip_atomic_load(ctr, __ATOMIC_ACQUIRE, __HIP_MEMORY_SCOPE_AGENT);
      __syncthreads();
      const short* Ah = h0seq + (size_t)i_cur * BH + row0 * Hdim;
      GEMM_H(Ah, Ah + 16 * Hdim, 0, 4)
      hout = h0seq + (size_t)i_next * BH;
    } else {
      ctr_poll2(ctr, 16u * (unsigned)(r + 1), 16u * (unsigned)r);
      if (tid == 0 && D < 257 && r >= D - 1)
        (void)__hip_atomic_load(ctr, __ATOMIC_ACQUIRE, __HIP_MEMORY_SCOPE_AGENT);
      __syncthreads();
      // x-part = h0(t=r) = h0seq[(r+1)%D]
      const short* Ax = h0seq + (size_t)i_next * BH + row0 * Hdim - Hdim;
      GEMM_H(Ax, Ax + 16 * Hdim, Hdim, 4)
      const short* Ah = h1seq + (size_t)i_cur * BH + row0 * Hdim;
      GEMM_H(Ah, Ah + 16 * Hdim, 0, 4)
      hout = h1seq + (size_t)i_next * BH;
    }

    // fused gates: D row = rg*4+j -> batch; lanes col<8 own h-col hcol0+col
    #pragma unroll
    for (int m = 0; m < 2; ++m) {
      #pragma unroll
      for (int j = 0; j < 4; ++j) {
        float fi  = acc[m][0][j] + biasv[0];
        float go  = acc[m][1][j] + biasv[1];
        float iv_ = __shfl_xor(fi, 8, 64);
        float ov_ = __shfl_xor(go, 8, 64);
        float fv = sigmf(fi), iv = sigmf(iv_);
        float gv = tanhf(go), ov = sigmf(ov_);
        float cn = fv * creg[m][j] + iv * gv;
        creg[m][j] = cn;
        float hn = ov * tanhf(cn);
        hfin[m][j] = hn;
        // pack 4 consecutive h-cols into one 8B agent-scope (MALL) store
        unsigned hv = (unsigned)(unsigned short)bf16_of(hn);
        unsigned p1 = hv | ((unsigned)__shfl_xor((int)hv, 1, 64) << 16);
        u64 p2 = (u64)p1 | ((u64)(unsigned)__shfl_xor((int)p1, 2, 64) << 32);
        if ((col & 3) == 0 && col < 8) {
          int b = wv * 32 + m * 16 + rg * 4 + j;
          __hip_atomic_store((u64*)(hout + b * Hdim + hcol0 + col), p2,
                             __ATOMIC_RELAXED, __HIP_MEMORY_SCOPE_AGENT);
        }
      }
    }
    ctr_arrive(ctr, myc);
    i_cur = i_next;
  }

  // epilogue: finals [L][2][B][H]
  if (col < 8) {
    #pragma unroll
    for (int m = 0; m < 2; ++m)
      #pragma unroll
      for (int j = 0; j < 4; ++j) {
        int b = wv * 32 + m * 16 + rg * 4 + j;
        finals[(layer * 2 + 0) * BH + b * Hdim + hcol0 + col] = hfin[m][j];
        finals[(layer * 2 + 1) * BH + b * Hdim + hcol0 + col] = creg[m][j];
      }
  }
}

__global__ __launch_bounds__(256) void k_outproj(const float* __restrict__ h1f,
    const float* __restrict__ Wout, const float* __restrict__ bout,
    float* __restrict__ out) {
  int b = blockIdx.x;
  int tid = threadIdx.x;
  float hv[4];
  #pragma unroll
  for (int j = 0; j < 4; ++j) hv[j] = h1f[b * Hdim + tid + j * 256];
  __shared__ float red[Odim][4];
  #pragma unroll
  for (int o = 0; o < Odim; ++o) {
    float p = 0.f;
    #pragma unroll
    for (int j = 0; j < 4; ++j) p += hv[j] * Wout[o * Hdim + tid + j * 256];
    #pragma unroll
    for (int s = 32; s > 0; s >>= 1) p += __shfl_down(p, s, 64);
    if ((tid & 63) == 0) red[o][tid >> 6] = p;
  }
  __syncthreads();
  if (tid < Odim)
    out[b * Odim + tid] = red[tid][0] + red[tid][1] + red[tid][2] + red[tid][3] + bout[tid];
}

extern "C" void kernel_launch(void* const* d_in, const int* in_sizes, int n_in,
                              void* d_out, int out_size, void* d_ws, size_t ws_size,
                              hipStream_t stream) {
  const float* x      = (const float*)d_in[0];
  const float* hidden = (const float*)d_in[1];
  const float* W0     = (const float*)d_in[2];
  const float* b0     = (const float*)d_in[3];
  const float* W1     = (const float*)d_in[4];
  const float* b1     = (const float*)d_in[5];
  const float* Wout   = (const float*)d_in[6];
  const float* bout   = (const float*)d_in[7];
  float* out = (float*)d_out;
  float* finals = out + Bdim * Odim;

  char* ws = (char*)d_ws;
  size_t off = 0;
  auto alloc = [&](size_t bytes) {
    void* p = ws + off;
    off += (bytes + 255) & ~(size_t)255;
    return p;
  };
  unsigned* ctr = (unsigned*)alloc(16 * 32 * sizeof(unsigned));  // 2KB padded
  const size_t seqSlotBytes = (size_t)BH * 2;                    // 0.5 MB
  size_t avail = (ws_size > off) ? (ws_size - off - 512) : 0;
  int D = (int)(avail / (2 * seqSlotBytes));
  if (D > 257) D = 257;
  if (D < 8) D = 8;  // ws proven >= 69MB in earlier rounds
  short* h0seq = (short*)alloc((size_t)D * seqSlotBytes);
  short* h1seq = (short*)alloc((size_t)D * seqSlotBytes);

  k_init<<<BH / 256, 256, 0, stream>>>(hidden, h0seq, h1seq);
  hipMemsetAsync(ctr, 0, 16 * 32 * sizeof(unsigned), stream);  // reset every launch

  const int ldsBytes = 32 * (2 * Hdim + 8) * 2;  // 131584 (L1 slice, the max)
  hipFuncSetAttribute((const void*)k_persist,
                      hipFuncAttributeMaxDynamicSharedMemorySize, ldsBytes);
  void* args[] = {(void*)&W0, (void*)&b0, (void*)&W1, (void*)&b1,
                  (void*)&hidden, (void*)&x,
                  (void*)&h0seq, (void*)&h1seq,
                  (void*)&finals, (void*)&ctr, (void*)&D};
  hipLaunchCooperativeKernel((const void*)k_persist, dim3(256), dim3(512),
                             args, ldsBytes, stream);

  k_outproj<<<Bdim, 256, 0, stream>>>(finals + 2 * BH, Wout, bout, out);
}